// Round 10
// baseline (307.075 us; speedup 1.0000x reference)
//
#include <hip/hip_runtime.h>

#define HEADS 24
#define KVH   6
#define HD    64
#define BB    2
#define SS    2048
#define DD    1536
#define KVD   384      // KVH*HD
#define QKD   1920     // DD + KVD (Q|K only; V lives in VT)
#define MM    4096     // BB*SS

typedef unsigned short ushort_t;
typedef __attribute__((ext_vector_type(8))) short short8;
typedef __attribute__((ext_vector_type(4))) short short4v;
typedef __attribute__((ext_vector_type(4))) float f32x4;

__device__ __forceinline__ ushort_t f2bf(float f) {
    union { float f; unsigned u; } v; v.f = f;
    return (ushort_t)((v.u + 0x8000u) >> 16);
}
__device__ __forceinline__ ushort_t f2bf_trunc(float f) {
    union { float f; unsigned u; } v; v.f = f;
    return (ushort_t)(v.u >> 16);
}
__device__ __forceinline__ unsigned pk2(float a, float b) {
    union { float f; unsigned u; } x, y; x.f = a; y.f = b;
    return ((x.u + 0x8000u) >> 16) | (((y.u + 0x8000u) >> 16) << 16);
}
#if __has_builtin(__builtin_amdgcn_exp2f)
#define EXP2(x) __builtin_amdgcn_exp2f(x)
#else
#define EXP2(x) exp2f(x)
#endif
// 16B frag read from an 8B-aligned LDS row (pitch 76): two b64 halves.
__device__ __forceinline__ short8 lds_frag8(const ushort_t* p) {
    short4v lo = *(const short4v*)p;
    short4v hi = *(const short4v*)(p + 4);
    return __builtin_shufflevector(lo, hi, 0, 1, 2, 3, 4, 5, 6, 7);
}
// async global->LDS, 16B per lane; lds ptr must be wave-uniform base.
__device__ __forceinline__ void glds16(const void* g, void* l) {
    __builtin_amdgcn_global_load_lds(
        (const __attribute__((address_space(1))) void*)g,
        (__attribute__((address_space(3))) void*)l, 16, 0, 0);
}

// ---------------------------------------------------------------------------
// K0: fused preprocessing — cvt X + 4x weight transpose-convert.
// ---------------------------------------------------------------------------
__device__ __forceinline__ void tconv_body(const float* __restrict__ in,
                                           ushort_t* __restrict__ out,
                                           int R, int C, int cb, int rb)
{
    __shared__ ushort_t tile[32][33];
    const int tx = threadIdx.x & 31, ty = threadIdx.x >> 5;
    const int c0 = cb * 32, r0 = rb * 32;
#pragma unroll
    for (int i = 0; i < 4; ++i)
        tile[ty + i * 8][tx] = f2bf(in[(size_t)(r0 + ty + i * 8) * C + c0 + tx]);
    __syncthreads();
#pragma unroll
    for (int i = 0; i < 4; ++i)
        out[(size_t)(c0 + ty + i * 8) * R + r0 + tx] = tile[tx][ty + i * 8];
}

#define NCVT (MM * DD / 4 / 256)     // 6144
__global__ __launch_bounds__(256) void k_prep(const float* __restrict__ HS,
                                              const float* __restrict__ Wq,
                                              const float* __restrict__ Wk,
                                              const float* __restrict__ Wv,
                                              const float* __restrict__ Wo,
                                              ushort_t* __restrict__ Xbf,
                                              ushort_t* __restrict__ Wqt,
                                              ushort_t* __restrict__ Wkt,
                                              ushort_t* __restrict__ Wvt,
                                              ushort_t* __restrict__ Wot)
{
    int bid = blockIdx.x;
    if (bid < NCVT) {
        int i = bid * 256 + threadIdx.x;
        float4 v = ((const float4*)HS)[i];
        uint2 o = { pk2(v.x, v.y), pk2(v.z, v.w) };
        ((uint2*)Xbf)[i] = o;
        return;
    }
    bid -= NCVT;
    if (bid < 2304) { tconv_body(Wq, Wqt, DD, DD,  bid % 48, bid / 48); return; }
    bid -= 2304;
    if (bid < 576)  { tconv_body(Wk, Wkt, DD, KVD, bid % 12, bid / 12); return; }
    bid -= 576;
    if (bid < 576)  { tconv_body(Wv, Wvt, DD, KVD, bid % 12, bid / 12); return; }
    bid -= 576;
    tconv_body(Wo, Wot, DD, DD, bid % 48, bid / 48);
}

// ---------------------------------------------------------------------------
// K1: fused projection dispatch.
//   bid <  480 : Q|K projection, 128x128 tiles + RoPE + Q-scale
//   bid >= 480 : V^T GEMM (VT[c][tok] = WvT @ X^T), 64x128 tiles (tail-last)
// ---------------------------------------------------------------------------
__global__ __launch_bounds__(256) void k_proj(const ushort_t* __restrict__ Xbf,
                                              const ushort_t* __restrict__ Wqt,
                                              const ushort_t* __restrict__ Wkt,
                                              const ushort_t* __restrict__ Wvt,
                                              const float* __restrict__ cosb,
                                              const float* __restrict__ sinb,
                                              ushort_t* __restrict__ QKVb,
                                              ushort_t* __restrict__ VT)
{
    __shared__ ushort_t As[128][32];
    __shared__ ushort_t Bs[128][32];
    const int t = threadIdx.x, lane = t & 63, wave = t >> 6;
    const int n16 = lane & 15, quad = lane >> 4;
    const int wr = wave >> 1, wc = wave & 1;
    const int srow = lane >> 2;
    const int scol = (lane & 3) * 8;

    if (blockIdx.x < 480) {
        // ---------------- Q|K projection ----------------
        const int nt = blockIdx.x % 15;
        const int n0 = nt * 128;
        const int m0 = (blockIdx.x / 15) * 128;
        const ushort_t* Bt; int nl, isq;
        if (nt < 12) { Bt = Wqt; nl = n0;      isq = 1; }
        else         { Bt = Wkt; nl = n0 - DD; isq = 0; }

        const size_t aoff0 = (size_t)(m0 + wave * 16 + srow) * DD + scol;
        const size_t aoff1 = (size_t)(m0 + (wave + 4) * 16 + srow) * DD + scol;
        const size_t boff0 = (size_t)(nl + wave * 16 + srow) * DD + scol;
        const size_t boff1 = (size_t)(nl + (wave + 4) * 16 + srow) * DD + scol;
        ushort_t* lA0 = &As[wave * 16][0];
        ushort_t* lA1 = &As[(wave + 4) * 16][0];
        ushort_t* lB0 = &Bs[wave * 16][0];
        ushort_t* lB1 = &Bs[(wave + 4) * 16][0];

        f32x4 acc[4][4] = {};
        for (int k0 = 0; k0 < DD; k0 += 32) {
            __syncthreads();
            glds16(Xbf + aoff0 + k0, lA0);
            glds16(Xbf + aoff1 + k0, lA1);
            glds16(Bt  + boff0 + k0, lB0);
            glds16(Bt  + boff1 + k0, lB1);
            __syncthreads();
            short8 af[4], bf8[4];
#pragma unroll
            for (int i = 0; i < 4; ++i) af[i]  = *(const short8*)&As[wr * 64 + i * 16 + n16][quad * 8];
#pragma unroll
            for (int j = 0; j < 4; ++j) bf8[j] = *(const short8*)&Bs[wc * 64 + j * 16 + n16][quad * 8];
#pragma unroll
            for (int i = 0; i < 4; ++i)
#pragma unroll
                for (int j = 0; j < 4; ++j)
                    acc[i][j] = __builtin_amdgcn_mfma_f32_16x16x32_bf16(af[i], bf8[j], acc[i][j], 0, 0, 0);
        }

        const float QSC = 0.18033688011112042f;   // 0.125 * log2(e)
#pragma unroll
        for (int i = 0; i < 4; ++i) {
#pragma unroll
            for (int r = 0; r < 4; ++r) {
                const int row = m0 + wr * 64 + i * 16 + quad * 4 + r;
                ushort_t* outp = QKVb + (size_t)row * QKD + n0 + wc * 64 + n16;
                float v0 = acc[i][0][r], v1 = acc[i][1][r];
                float v2 = acc[i][2][r], v3 = acc[i][3][r];
                {   // partial RoPE on head dims 0..31 (Q and K)
                    const int s = row & (SS - 1);
                    float c0 = cosb[s * 32 + n16],      s0 = sinb[s * 32 + n16];
                    float c1 = cosb[s * 32 + 16 + n16], s1 = sinb[s * 32 + 16 + n16];
                    float nr = v0 * c0 - v1 * s0;
                    float ni = v1 * c1 + v0 * s1;
                    v0 = nr; v1 = ni;
                }
                if (isq) { v0 *= QSC; v1 *= QSC; v2 *= QSC; v3 *= QSC; }
                outp[0]  = f2bf(v0);
                outp[16] = f2bf(v1);
                outp[32] = f2bf(v2);
                outp[48] = f2bf(v3);
            }
        }
    } else {
        // ---------------- V^T GEMM ----------------
        const int vb = blockIdx.x - 480;
        const int n0 = (vb & 31) * 128;    // tokens
        const int m0 = (vb >> 5) * 64;     // channels c

        const size_t aoff  = (size_t)(m0 + wave * 16 + srow) * DD + scol;
        const size_t boff0 = (size_t)(n0 + wave * 32 + srow) * DD + scol;
        const size_t boff1 = boff0 + (size_t)16 * DD;
        ushort_t* lA  = &As[wave * 16][0];
        ushort_t* lB0 = &Bs[wave * 32][0];
        ushort_t* lB1 = &Bs[wave * 32 + 16][0];

        f32x4 acc[2][4] = {};
        for (int k0 = 0; k0 < DD; k0 += 32) {
            __syncthreads();
            glds16(Wvt + aoff  + k0, lA);
            glds16(Xbf + boff0 + k0, lB0);
            glds16(Xbf + boff1 + k0, lB1);
            __syncthreads();
            short8 af[2], bf8[4];
#pragma unroll
            for (int i = 0; i < 2; ++i) af[i]  = *(const short8*)&As[wr * 32 + i * 16 + n16][quad * 8];
#pragma unroll
            for (int j = 0; j < 4; ++j) bf8[j] = *(const short8*)&Bs[wc * 64 + j * 16 + n16][quad * 8];
#pragma unroll
            for (int i = 0; i < 2; ++i)
#pragma unroll
                for (int j = 0; j < 4; ++j)
                    acc[i][j] = __builtin_amdgcn_mfma_f32_16x16x32_bf16(af[i], bf8[j], acc[i][j], 0, 0, 0);
        }

        const int b = n0 >> 11;            // token tile never straddles batch
#pragma unroll
        for (int i = 0; i < 2; ++i)
#pragma unroll
            for (int r = 0; r < 4; ++r) {
                const int c = m0 + wr * 32 + i * 16 + quad * 4 + r;
                ushort_t* op = VT + ((size_t)b * KVD + c) * SS + (n0 & (SS - 1)) + wc * 64 + n16;
#pragma unroll
                for (int j = 0; j < 4; ++j)
                    op[j * 16] = f2bf(acc[i][j][r]);
            }
    }
}

// ---------------------------------------------------------------------------
// K3: MFMA bf16 flash attention, NO-MAX softmax, 16 q/wave, 64 q/block.
// Smaller q-tile trades 2x K/V L2 re-reads (cheap: ~8 of 34 TB/s) for
// occupancy: LDS 29.2 KB -> 5 blocks/CU, grid 1536 -> ~20 waves/CU resident
// (was ~12), hiding the global-load latency between the staging barriers.
// LDS pitch 76: frag reads & P traffic conflict-free-ish (<=2-way).
// ---------------------------------------------------------------------------
__global__ __launch_bounds__(256) void k_attn(const ushort_t* __restrict__ QKVb,
                                              const ushort_t* __restrict__ VT,
                                              ushort_t* __restrict__ AOb)
{
    __shared__ __align__(16) ushort_t Ks[64][76];
    __shared__ __align__(16) ushort_t Vs[64][76];   // Vs[d][ktok]
    __shared__ __align__(16) ushort_t Ps[64][76];

    const int t    = threadIdx.x;
    const int wave = t >> 6;
    const int quad = (t >> 4) & 3;
    const int n16  = t & 15;
    const int q0   = blockIdx.x * 64;
    const int h    = blockIdx.y;
    const int b    = blockIdx.z;
    const int kh   = h >> 2;

    const int sr = t >> 2;            // 0..63 staging row
    const int sc = (t & 3) * 8;       // K staging col
    const int vc = (t & 3) * 16;      // V staging col

    // loop-invariant Q A-frags from global (pre-scaled by 0.125*log2e)
    short8 qf[2];
#pragma unroll
    for (int kc = 0; kc < 2; ++kc)
        qf[kc] = *(const short8*)(QKVb +
            (size_t)(b * SS + q0 + wave * 16 + n16) * QKD +
            h * HD + kc * 32 + quad * 8);

    float l_p[4] = {};                // per-lane partial row sums
    f32x4 acc_o[4] = {};

    const ushort_t* Kbase = QKVb + (size_t)(b * SS) * QKD + DD + kh * HD;
    const ushort_t* Vbase = VT + ((size_t)b * KVD + kh * 64) * SS;

    for (int kt = 0; kt < SS / 64; ++kt) {
        const int k0 = kt * 64;
        __syncthreads();   // prev-tile readers of Ks/Vs done
        {
            const ushort_t* Kg = Kbase + (size_t)(k0 + sr) * QKD + sc;
            uint4 kv0 = *(const uint4*)(Kg);
            uint4 kv1 = *(const uint4*)(Kg + 32);
            *(uint2*)&Ks[sr][sc]      = make_uint2(kv0.x, kv0.y);
            *(uint2*)&Ks[sr][sc + 4]  = make_uint2(kv0.z, kv0.w);
            *(uint2*)&Ks[sr][sc + 32] = make_uint2(kv1.x, kv1.y);
            *(uint2*)&Ks[sr][sc + 36] = make_uint2(kv1.z, kv1.w);
            const ushort_t* Vg = Vbase + (size_t)sr * SS + k0 + vc;
            uint4 vv0 = *(const uint4*)(Vg);
            uint4 vv1 = *(const uint4*)(Vg + 8);
            *(uint2*)&Vs[sr][vc]      = make_uint2(vv0.x, vv0.y);
            *(uint2*)&Vs[sr][vc + 4]  = make_uint2(vv0.z, vv0.w);
            *(uint2*)&Vs[sr][vc + 8]  = make_uint2(vv1.x, vv1.y);
            *(uint2*)&Vs[sr][vc + 12] = make_uint2(vv1.z, vv1.w);
        }
        __syncthreads();

        // ---- QK^T: S[16q][64k] per wave ----
        f32x4 s_acc[4] = {};
#pragma unroll
        for (int kc = 0; kc < 2; ++kc) {
#pragma unroll
            for (int jj = 0; jj < 4; ++jj) {
                short8 bf = lds_frag8(&Ks[jj * 16 + n16][kc * 32 + quad * 8]);
                s_acc[jj] = __builtin_amdgcn_mfma_f32_16x16x32_bf16(
                    qf[kc], bf, s_acc[jj], 0, 0, 0);
            }
        }

        // ---- p = 2^s; accumulate partial l; P -> wave-private LDS rows ----
#pragma unroll
        for (int r = 0; r < 4; ++r) {
            float p0 = EXP2(s_acc[0][r]);
            float p1 = EXP2(s_acc[1][r]);
            float p2 = EXP2(s_acc[2][r]);
            float p3 = EXP2(s_acc[3][r]);
            ushort_t* pr = &Ps[wave * 16 + quad * 4 + r][n16];
            pr[0]  = f2bf_trunc(p0);
            pr[16] = f2bf_trunc(p1);
            pr[32] = f2bf_trunc(p2);
            pr[48] = f2bf_trunc(p3);
            l_p[r] += (p0 + p1) + (p2 + p3);
        }

        // ---- PV (Ps rows wave-private; same-wave RAW via lgkmcnt) ----
#pragma unroll
        for (int kc = 0; kc < 2; ++kc) {
            short8 pa = lds_frag8(&Ps[wave * 16 + n16][kc * 32 + quad * 8]);
#pragma unroll
            for (int dd = 0; dd < 4; ++dd) {
                short8 vb = lds_frag8(&Vs[dd * 16 + n16][kc * 32 + quad * 8]);
                acc_o[dd] = __builtin_amdgcn_mfma_f32_16x16x32_bf16(
                    pa, vb, acc_o[dd], 0, 0, 0);
            }
        }
    }

    // ---- epilogue: one lane-reduction of l, then O/l ----
    float inv[4];
#pragma unroll
    for (int r = 0; r < 4; ++r) {
        float s = l_p[r];
#pragma unroll
        for (int msk = 1; msk < 16; msk <<= 1)
            s += __shfl_xor(s, msk);
        inv[r] = 1.0f / s;
    }
#pragma unroll
    for (int dd = 0; dd < 4; ++dd)
#pragma unroll
        for (int r = 0; r < 4; ++r) {
            int q = q0 + wave * 16 + quad * 4 + r;
            AOb[(size_t)(b * SS + q) * DD + h * HD + dd * 16 + n16] =
                f2bf(acc_o[dd][r] * inv[r]);
        }
}

// ---------------------------------------------------------------------------
// K4: MFMA out-proj.  out[MM][DD](fp32) = AOb @ Wot^T + bo + HS.
// 64m x 128n tiles, grid (DD/128=12) x (MM/64=64) = 768 = exactly 3/CU.
// ---------------------------------------------------------------------------
__global__ __launch_bounds__(256) void k_out_mfma(const ushort_t* __restrict__ AOb,
                                                  const ushort_t* __restrict__ Wot,
                                                  const float* __restrict__ bo,
                                                  const float* __restrict__ HS,
                                                  float* __restrict__ out)
{
    __shared__ ushort_t As[64][32];    // AOb rows (m)
    __shared__ ushort_t Bs[128][32];   // Wot rows (n)
    const int t = threadIdx.x, lane = t & 63, wave = t >> 6;
    const int n16 = lane & 15, quad = lane >> 4;
    const int wr = wave >> 1, wc = wave & 1;
    const int n0 = blockIdx.x * 128;
    const int m0 = blockIdx.y * 64;

    const int srow = lane >> 2;
    const int scol = (lane & 3) * 8;
    const size_t aoff  = (size_t)(m0 + wave * 16 + srow) * DD + scol;
    const size_t boff0 = (size_t)(n0 + wave * 32 + srow) * DD + scol;
    const size_t boff1 = boff0 + (size_t)16 * DD;
    ushort_t* lA  = &As[wave * 16][0];
    ushort_t* lB0 = &Bs[wave * 32][0];
    ushort_t* lB1 = &Bs[wave * 32 + 16][0];

    f32x4 acc[2][4] = {};
    for (int k0 = 0; k0 < DD; k0 += 32) {
        __syncthreads();
        glds16(AOb + aoff  + k0, lA);
        glds16(Wot + boff0 + k0, lB0);
        glds16(Wot + boff1 + k0, lB1);
        __syncthreads();
        short8 af[2], bf8[4];
#pragma unroll
        for (int i = 0; i < 2; ++i) af[i]  = *(const short8*)&As[wr * 32 + i * 16 + n16][quad * 8];
#pragma unroll
        for (int j = 0; j < 4; ++j) bf8[j] = *(const short8*)&Bs[wc * 64 + j * 16 + n16][quad * 8];
#pragma unroll
        for (int i = 0; i < 2; ++i)
#pragma unroll
            for (int j = 0; j < 4; ++j)
                acc[i][j] = __builtin_amdgcn_mfma_f32_16x16x32_bf16(af[i], bf8[j], acc[i][j], 0, 0, 0);
    }

    const int colb = n0 + wc * 64 + n16;
    float bo4[4];
#pragma unroll
    for (int j = 0; j < 4; ++j) bo4[j] = bo[colb + j * 16];
#pragma unroll
    for (int i = 0; i < 2; ++i) {
#pragma unroll
        for (int r = 0; r < 4; ++r) {
            const int row = m0 + wr * 32 + i * 16 + quad * 4 + r;
            float* op = out + (size_t)row * DD + colb;
            const float* hp = HS + (size_t)row * DD + colb;
#pragma unroll
            for (int j = 0; j < 4; ++j)
                op[j * 16] = acc[i][j][r] + bo4[j] + hp[j * 16];
        }
    }
}

extern "C" void kernel_launch(void* const* d_in, const int* in_sizes, int n_in,
                              void* d_out, int out_size, void* d_ws, size_t ws_size,
                              hipStream_t stream)
{
    const float* HS   = (const float*)d_in[0];
    const float* cosb = (const float*)d_in[1];
    const float* sinb = (const float*)d_in[2];
    const float* Wq   = (const float*)d_in[3];
    const float* Wk   = (const float*)d_in[4];
    const float* Wv   = (const float*)d_in[5];
    const float* Wo   = (const float*)d_in[6];
    const float* bo   = (const float*)d_in[7];
    float* out = (float*)d_out;

    ushort_t* Xbf  = (ushort_t*)d_ws;                  // [MM][DD]
    ushort_t* QKVb = Xbf  + (size_t)MM * DD;           // [MM][QKD]
    ushort_t* AOb  = QKVb + (size_t)MM * QKD;          // [MM][DD]
    ushort_t* Wqt  = AOb  + (size_t)MM * DD;           // [DD][DD]
    ushort_t* Wkt  = Wqt  + (size_t)DD * DD;           // [KVD][DD]
    ushort_t* Wvt  = Wkt  + (size_t)KVD * DD;          // [KVD][DD]
    ushort_t* Wot  = Wvt  + (size_t)KVD * DD;          // [DD][DD]
    ushort_t* VT   = Wot  + (size_t)DD * DD;           // [BB][KVD][SS]

    const int nprep = NCVT + 2304 + 576 + 576 + 2304;
    k_prep    <<<dim3(nprep), 256, 0, stream>>>(HS, Wq, Wk, Wv, Wo,
                                                Xbf, Wqt, Wkt, Wvt, Wot);
    k_proj    <<<dim3(480 + 192), 256, 0, stream>>>(Xbf, Wqt, Wkt, Wvt,
                                                    cosb, sinb, QKVb, VT);
    k_attn    <<<dim3(SS / 64, HEADS, BB), 256, 0, stream>>>(QKVb, VT, AOb);
    k_out_mfma<<<dim3(DD / 128, MM / 64),  256, 0, stream>>>(AOb, Wot, bo, HS, out);
}

// Round 11
// 269.162 us; speedup vs baseline: 1.1409x; 1.1409x over previous
//
#include <hip/hip_runtime.h>

#define HEADS 24
#define KVH   6
#define HD    64
#define BB    2
#define SS    2048
#define DD    1536
#define KVD   384      // KVH*HD
#define QKD   1920     // DD + KVD (Q|K only; V lives in VT)
#define MM    4096     // BB*SS

typedef unsigned short ushort_t;
typedef __attribute__((ext_vector_type(8))) short short8;
typedef __attribute__((ext_vector_type(4))) short short4v;
typedef __attribute__((ext_vector_type(4))) float f32x4;

__device__ __forceinline__ ushort_t f2bf(float f) {
    union { float f; unsigned u; } v; v.f = f;
    return (ushort_t)((v.u + 0x8000u) >> 16);
}
__device__ __forceinline__ ushort_t f2bf_trunc(float f) {
    union { float f; unsigned u; } v; v.f = f;
    return (ushort_t)(v.u >> 16);
}
__device__ __forceinline__ unsigned pk2(float a, float b) {
    union { float f; unsigned u; } x, y; x.f = a; y.f = b;
    return ((x.u + 0x8000u) >> 16) | (((y.u + 0x8000u) >> 16) << 16);
}
// Schraudolph fast 2^s: linear-in-mantissa bit trick, ~±3.5% relative,
// centered so softmax normalization cancels the common mode.
// Full-rate: 1 fma + 1 cvt vs quarter-rate v_exp_f32.
__device__ __forceinline__ float fexp2(float s) {
    float t = fmaf(s, 8388608.0f, 1065055420.0f);   // (127 - 0.0355) * 2^23
    union { int i; float f; } v; v.i = (int)t;
    return v.f;
}
// 16B frag read from an 8B-aligned LDS row (pitch 76): two b64 halves.
__device__ __forceinline__ short8 lds_frag8(const ushort_t* p) {
    short4v lo = *(const short4v*)p;
    short4v hi = *(const short4v*)(p + 4);
    return __builtin_shufflevector(lo, hi, 0, 1, 2, 3, 4, 5, 6, 7);
}
// async global->LDS, 16B per lane; lds ptr must be wave-uniform base.
__device__ __forceinline__ void glds16(const void* g, void* l) {
    __builtin_amdgcn_global_load_lds(
        (const __attribute__((address_space(1))) void*)g,
        (__attribute__((address_space(3))) void*)l, 16, 0, 0);
}

// ---------------------------------------------------------------------------
// K0: fused preprocessing — cvt X + 4x weight transpose-convert.
// ---------------------------------------------------------------------------
__device__ __forceinline__ void tconv_body(const float* __restrict__ in,
                                           ushort_t* __restrict__ out,
                                           int R, int C, int cb, int rb)
{
    __shared__ ushort_t tile[32][33];
    const int tx = threadIdx.x & 31, ty = threadIdx.x >> 5;
    const int c0 = cb * 32, r0 = rb * 32;
#pragma unroll
    for (int i = 0; i < 4; ++i)
        tile[ty + i * 8][tx] = f2bf(in[(size_t)(r0 + ty + i * 8) * C + c0 + tx]);
    __syncthreads();
#pragma unroll
    for (int i = 0; i < 4; ++i)
        out[(size_t)(c0 + ty + i * 8) * R + r0 + tx] = tile[tx][ty + i * 8];
}

#define NCVT (MM * DD / 4 / 256)     // 6144
__global__ __launch_bounds__(256) void k_prep(const float* __restrict__ HS,
                                              const float* __restrict__ Wq,
                                              const float* __restrict__ Wk,
                                              const float* __restrict__ Wv,
                                              const float* __restrict__ Wo,
                                              ushort_t* __restrict__ Xbf,
                                              ushort_t* __restrict__ Wqt,
                                              ushort_t* __restrict__ Wkt,
                                              ushort_t* __restrict__ Wvt,
                                              ushort_t* __restrict__ Wot)
{
    int bid = blockIdx.x;
    if (bid < NCVT) {
        int i = bid * 256 + threadIdx.x;
        float4 v = ((const float4*)HS)[i];
        uint2 o = { pk2(v.x, v.y), pk2(v.z, v.w) };
        ((uint2*)Xbf)[i] = o;
        return;
    }
    bid -= NCVT;
    if (bid < 2304) { tconv_body(Wq, Wqt, DD, DD,  bid % 48, bid / 48); return; }
    bid -= 2304;
    if (bid < 576)  { tconv_body(Wk, Wkt, DD, KVD, bid % 12, bid / 12); return; }
    bid -= 576;
    if (bid < 576)  { tconv_body(Wv, Wvt, DD, KVD, bid % 12, bid / 12); return; }
    bid -= 576;
    tconv_body(Wo, Wot, DD, DD, bid % 48, bid / 48);
}

// ---------------------------------------------------------------------------
// K1: fused projection dispatch.
//   bid <  480 : Q|K projection, 128x128 tiles + RoPE + Q-scale
//   bid >= 480 : V^T GEMM (VT[c][tok] = WvT @ X^T), 64x128 tiles (tail-last)
// ---------------------------------------------------------------------------
__global__ __launch_bounds__(256) void k_proj(const ushort_t* __restrict__ Xbf,
                                              const ushort_t* __restrict__ Wqt,
                                              const ushort_t* __restrict__ Wkt,
                                              const ushort_t* __restrict__ Wvt,
                                              const float* __restrict__ cosb,
                                              const float* __restrict__ sinb,
                                              ushort_t* __restrict__ QKVb,
                                              ushort_t* __restrict__ VT)
{
    __shared__ ushort_t As[128][32];
    __shared__ ushort_t Bs[128][32];
    const int t = threadIdx.x, lane = t & 63, wave = t >> 6;
    const int n16 = lane & 15, quad = lane >> 4;
    const int wr = wave >> 1, wc = wave & 1;
    const int srow = lane >> 2;
    const int scol = (lane & 3) * 8;

    if (blockIdx.x < 480) {
        // ---------------- Q|K projection ----------------
        const int nt = blockIdx.x % 15;
        const int n0 = nt * 128;
        const int m0 = (blockIdx.x / 15) * 128;
        const ushort_t* Bt; int nl, isq;
        if (nt < 12) { Bt = Wqt; nl = n0;      isq = 1; }
        else         { Bt = Wkt; nl = n0 - DD; isq = 0; }

        const size_t aoff0 = (size_t)(m0 + wave * 16 + srow) * DD + scol;
        const size_t aoff1 = (size_t)(m0 + (wave + 4) * 16 + srow) * DD + scol;
        const size_t boff0 = (size_t)(nl + wave * 16 + srow) * DD + scol;
        const size_t boff1 = (size_t)(nl + (wave + 4) * 16 + srow) * DD + scol;
        ushort_t* lA0 = &As[wave * 16][0];
        ushort_t* lA1 = &As[(wave + 4) * 16][0];
        ushort_t* lB0 = &Bs[wave * 16][0];
        ushort_t* lB1 = &Bs[(wave + 4) * 16][0];

        f32x4 acc[4][4] = {};
        for (int k0 = 0; k0 < DD; k0 += 32) {
            __syncthreads();
            glds16(Xbf + aoff0 + k0, lA0);
            glds16(Xbf + aoff1 + k0, lA1);
            glds16(Bt  + boff0 + k0, lB0);
            glds16(Bt  + boff1 + k0, lB1);
            __syncthreads();
            short8 af[4], bf8[4];
#pragma unroll
            for (int i = 0; i < 4; ++i) af[i]  = *(const short8*)&As[wr * 64 + i * 16 + n16][quad * 8];
#pragma unroll
            for (int j = 0; j < 4; ++j) bf8[j] = *(const short8*)&Bs[wc * 64 + j * 16 + n16][quad * 8];
#pragma unroll
            for (int i = 0; i < 4; ++i)
#pragma unroll
                for (int j = 0; j < 4; ++j)
                    acc[i][j] = __builtin_amdgcn_mfma_f32_16x16x32_bf16(af[i], bf8[j], acc[i][j], 0, 0, 0);
        }

        const float QSC = 0.18033688011112042f;   // 0.125 * log2(e)
#pragma unroll
        for (int i = 0; i < 4; ++i) {
#pragma unroll
            for (int r = 0; r < 4; ++r) {
                const int row = m0 + wr * 64 + i * 16 + quad * 4 + r;
                ushort_t* outp = QKVb + (size_t)row * QKD + n0 + wc * 64 + n16;
                float v0 = acc[i][0][r], v1 = acc[i][1][r];
                float v2 = acc[i][2][r], v3 = acc[i][3][r];
                {   // partial RoPE on head dims 0..31 (Q and K)
                    const int s = row & (SS - 1);
                    float c0 = cosb[s * 32 + n16],      s0 = sinb[s * 32 + n16];
                    float c1 = cosb[s * 32 + 16 + n16], s1 = sinb[s * 32 + 16 + n16];
                    float nr = v0 * c0 - v1 * s0;
                    float ni = v1 * c1 + v0 * s1;
                    v0 = nr; v1 = ni;
                }
                if (isq) { v0 *= QSC; v1 *= QSC; v2 *= QSC; v3 *= QSC; }
                outp[0]  = f2bf(v0);
                outp[16] = f2bf(v1);
                outp[32] = f2bf(v2);
                outp[48] = f2bf(v3);
            }
        }
    } else {
        // ---------------- V^T GEMM ----------------
        const int vb = blockIdx.x - 480;
        const int n0 = (vb & 31) * 128;    // tokens
        const int m0 = (vb >> 5) * 64;     // channels c

        const size_t aoff  = (size_t)(m0 + wave * 16 + srow) * DD + scol;
        const size_t boff0 = (size_t)(n0 + wave * 32 + srow) * DD + scol;
        const size_t boff1 = boff0 + (size_t)16 * DD;
        ushort_t* lA  = &As[wave * 16][0];
        ushort_t* lB0 = &Bs[wave * 32][0];
        ushort_t* lB1 = &Bs[wave * 32 + 16][0];

        f32x4 acc[2][4] = {};
        for (int k0 = 0; k0 < DD; k0 += 32) {
            __syncthreads();
            glds16(Wvt + aoff  + k0, lA);
            glds16(Xbf + boff0 + k0, lB0);
            glds16(Xbf + boff1 + k0, lB1);
            __syncthreads();
            short8 af[2], bf8[4];
#pragma unroll
            for (int i = 0; i < 2; ++i) af[i]  = *(const short8*)&As[wr * 32 + i * 16 + n16][quad * 8];
#pragma unroll
            for (int j = 0; j < 4; ++j) bf8[j] = *(const short8*)&Bs[wc * 64 + j * 16 + n16][quad * 8];
#pragma unroll
            for (int i = 0; i < 2; ++i)
#pragma unroll
                for (int j = 0; j < 4; ++j)
                    acc[i][j] = __builtin_amdgcn_mfma_f32_16x16x32_bf16(af[i], bf8[j], acc[i][j], 0, 0, 0);
        }

        const int b = n0 >> 11;            // token tile never straddles batch
#pragma unroll
        for (int i = 0; i < 2; ++i)
#pragma unroll
            for (int r = 0; r < 4; ++r) {
                const int c = m0 + wr * 32 + i * 16 + quad * 4 + r;
                ushort_t* op = VT + ((size_t)b * KVD + c) * SS + (n0 & (SS - 1)) + wc * 64 + n16;
#pragma unroll
                for (int j = 0; j < 4; ++j)
                    op[j * 16] = f2bf(acc[i][j][r]);
            }
    }
}

// ---------------------------------------------------------------------------
// K3: MFMA bf16 flash attention — R8 shape (the tile-sweep optimum:
// 128q/block, 32q/wave) + Schraudolph fast-exp2 softmax.
// LDS pitch 76; P stride 76.  LDS 38.0 KB, VGPR ~64, grid 768 = 3/CU.
// ---------------------------------------------------------------------------
__global__ __launch_bounds__(256) void k_attn(const ushort_t* __restrict__ QKVb,
                                              const ushort_t* __restrict__ VT,
                                              ushort_t* __restrict__ AOb)
{
    __shared__ __align__(16) ushort_t Ks[64][76];
    __shared__ __align__(16) ushort_t Vs[64][76];   // Vs[d][ktok]
    __shared__ __align__(16) ushort_t Ps[128][76];

    const int t    = threadIdx.x;
    const int wave = t >> 6;
    const int quad = (t >> 4) & 3;
    const int n16  = t & 15;
    const int q0   = blockIdx.x * 128;
    const int h    = blockIdx.y;
    const int b    = blockIdx.z;
    const int kh   = h >> 2;

    const int sr = t >> 2;            // 0..63 staging row
    const int sc = (t & 3) * 8;       // K staging col
    const int vc = (t & 3) * 16;      // V staging col

    // loop-invariant Q A-frags from global (pre-scaled by 0.125*log2e)
    short8 qf[2][2];
#pragma unroll
    for (int m = 0; m < 2; ++m)
#pragma unroll
        for (int kc = 0; kc < 2; ++kc)
            qf[m][kc] = *(const short8*)(QKVb +
                (size_t)(b * SS + q0 + wave * 32 + m * 16 + n16) * QKD +
                h * HD + kc * 32 + quad * 8);

    float l_p[2][4] = {};             // per-lane partial row sums
    f32x4 acc_o[2][4] = {};

    const ushort_t* Kbase = QKVb + (size_t)(b * SS) * QKD + DD + kh * HD;
    const ushort_t* Vbase = VT + ((size_t)b * KVD + kh * 64) * SS;

    for (int kt = 0; kt < SS / 64; ++kt) {
        const int k0 = kt * 64;
        __syncthreads();   // prev-tile readers of Ks/Vs done
        {
            const ushort_t* Kg = Kbase + (size_t)(k0 + sr) * QKD + sc;
            uint4 kv0 = *(const uint4*)(Kg);
            uint4 kv1 = *(const uint4*)(Kg + 32);
            *(uint2*)&Ks[sr][sc]      = make_uint2(kv0.x, kv0.y);
            *(uint2*)&Ks[sr][sc + 4]  = make_uint2(kv0.z, kv0.w);
            *(uint2*)&Ks[sr][sc + 32] = make_uint2(kv1.x, kv1.y);
            *(uint2*)&Ks[sr][sc + 36] = make_uint2(kv1.z, kv1.w);
            const ushort_t* Vg = Vbase + (size_t)sr * SS + k0 + vc;
            uint4 vv0 = *(const uint4*)(Vg);
            uint4 vv1 = *(const uint4*)(Vg + 8);
            *(uint2*)&Vs[sr][vc]      = make_uint2(vv0.x, vv0.y);
            *(uint2*)&Vs[sr][vc + 4]  = make_uint2(vv0.z, vv0.w);
            *(uint2*)&Vs[sr][vc + 8]  = make_uint2(vv1.x, vv1.y);
            *(uint2*)&Vs[sr][vc + 12] = make_uint2(vv1.z, vv1.w);
        }
        __syncthreads();

        // ---- QK^T: S[32q][64k] per wave ----
        f32x4 s_acc[2][4] = {};
#pragma unroll
        for (int kc = 0; kc < 2; ++kc) {
            short8 bf[4];
#pragma unroll
            for (int jj = 0; jj < 4; ++jj)
                bf[jj] = lds_frag8(&Ks[jj * 16 + n16][kc * 32 + quad * 8]);
#pragma unroll
            for (int m = 0; m < 2; ++m)
#pragma unroll
                for (int jj = 0; jj < 4; ++jj)
                    s_acc[m][jj] = __builtin_amdgcn_mfma_f32_16x16x32_bf16(
                        qf[m][kc], bf[jj], s_acc[m][jj], 0, 0, 0);
        }

        // ---- p = 2^s via fast bit-trick; partial l; P -> LDS ----
#pragma unroll
        for (int m = 0; m < 2; ++m)
#pragma unroll
            for (int r = 0; r < 4; ++r) {
                float p0 = fexp2(s_acc[m][0][r]);
                float p1 = fexp2(s_acc[m][1][r]);
                float p2 = fexp2(s_acc[m][2][r]);
                float p3 = fexp2(s_acc[m][3][r]);
                ushort_t* pr = &Ps[wave * 32 + m * 16 + quad * 4 + r][n16];
                pr[0]  = f2bf_trunc(p0);
                pr[16] = f2bf_trunc(p1);
                pr[32] = f2bf_trunc(p2);
                pr[48] = f2bf_trunc(p3);
                l_p[m][r] += (p0 + p1) + (p2 + p3);
            }

        // ---- PV (Ps rows wave-private; same-wave RAW via lgkmcnt) ----
#pragma unroll
        for (int kc = 0; kc < 2; ++kc) {
            short8 vb[4];
#pragma unroll
            for (int dd = 0; dd < 4; ++dd)
                vb[dd] = lds_frag8(&Vs[dd * 16 + n16][kc * 32 + quad * 8]);
#pragma unroll
            for (int m = 0; m < 2; ++m) {
                short8 pa = lds_frag8(&Ps[wave * 32 + m * 16 + n16][kc * 32 + quad * 8]);
#pragma unroll
                for (int dd = 0; dd < 4; ++dd)
                    acc_o[m][dd] = __builtin_amdgcn_mfma_f32_16x16x32_bf16(
                        pa, vb[dd], acc_o[m][dd], 0, 0, 0);
            }
        }
    }

    // ---- epilogue: one lane-reduction of l, then O/l ----
#pragma unroll
    for (int m = 0; m < 2; ++m) {
        float inv[4];
#pragma unroll
        for (int r = 0; r < 4; ++r) {
            float s = l_p[m][r];
#pragma unroll
            for (int msk = 1; msk < 16; msk <<= 1)
                s += __shfl_xor(s, msk);
            inv[r] = 1.0f / s;
        }
#pragma unroll
        for (int dd = 0; dd < 4; ++dd)
#pragma unroll
            for (int r = 0; r < 4; ++r) {
                int q = q0 + wave * 32 + m * 16 + quad * 4 + r;
                AOb[(size_t)(b * SS + q) * DD + h * HD + dd * 16 + n16] =
                    f2bf(acc_o[m][dd][r] * inv[r]);
            }
    }
}

// ---------------------------------------------------------------------------
// K4: MFMA out-proj.  out[MM][DD](fp32) = AOb @ Wot^T + bo + HS.
// 64m x 128n tiles, grid (DD/128=12) x (MM/64=64) = 768 = exactly 3/CU.
// ---------------------------------------------------------------------------
__global__ __launch_bounds__(256) void k_out_mfma(const ushort_t* __restrict__ AOb,
                                                  const ushort_t* __restrict__ Wot,
                                                  const float* __restrict__ bo,
                                                  const float* __restrict__ HS,
                                                  float* __restrict__ out)
{
    __shared__ ushort_t As[64][32];    // AOb rows (m)
    __shared__ ushort_t Bs[128][32];   // Wot rows (n)
    const int t = threadIdx.x, lane = t & 63, wave = t >> 6;
    const int n16 = lane & 15, quad = lane >> 4;
    const int wr = wave >> 1, wc = wave & 1;
    const int n0 = blockIdx.x * 128;
    const int m0 = blockIdx.y * 64;

    const int srow = lane >> 2;
    const int scol = (lane & 3) * 8;
    const size_t aoff  = (size_t)(m0 + wave * 16 + srow) * DD + scol;
    const size_t boff0 = (size_t)(n0 + wave * 32 + srow) * DD + scol;
    const size_t boff1 = boff0 + (size_t)16 * DD;
    ushort_t* lA  = &As[wave * 16][0];
    ushort_t* lB0 = &Bs[wave * 32][0];
    ushort_t* lB1 = &Bs[wave * 32 + 16][0];

    f32x4 acc[2][4] = {};
    for (int k0 = 0; k0 < DD; k0 += 32) {
        __syncthreads();
        glds16(AOb + aoff  + k0, lA);
        glds16(Wot + boff0 + k0, lB0);
        glds16(Wot + boff1 + k0, lB1);
        __syncthreads();
        short8 af[2], bf8[4];
#pragma unroll
        for (int i = 0; i < 2; ++i) af[i]  = *(const short8*)&As[wr * 32 + i * 16 + n16][quad * 8];
#pragma unroll
        for (int j = 0; j < 4; ++j) bf8[j] = *(const short8*)&Bs[wc * 64 + j * 16 + n16][quad * 8];
#pragma unroll
        for (int i = 0; i < 2; ++i)
#pragma unroll
            for (int j = 0; j < 4; ++j)
                acc[i][j] = __builtin_amdgcn_mfma_f32_16x16x32_bf16(af[i], bf8[j], acc[i][j], 0, 0, 0);
    }

    const int colb = n0 + wc * 64 + n16;
    float bo4[4];
#pragma unroll
    for (int j = 0; j < 4; ++j) bo4[j] = bo[colb + j * 16];
#pragma unroll
    for (int i = 0; i < 2; ++i) {
#pragma unroll
        for (int r = 0; r < 4; ++r) {
            const int row = m0 + wr * 32 + i * 16 + quad * 4 + r;
            float* op = out + (size_t)row * DD + colb;
            const float* hp = HS + (size_t)row * DD + colb;
#pragma unroll
            for (int j = 0; j < 4; ++j)
                op[j * 16] = acc[i][j][r] + bo4[j] + hp[j * 16];
        }
    }
}

extern "C" void kernel_launch(void* const* d_in, const int* in_sizes, int n_in,
                              void* d_out, int out_size, void* d_ws, size_t ws_size,
                              hipStream_t stream)
{
    const float* HS   = (const float*)d_in[0];
    const float* cosb = (const float*)d_in[1];
    const float* sinb = (const float*)d_in[2];
    const float* Wq   = (const float*)d_in[3];
    const float* Wk   = (const float*)d_in[4];
    const float* Wv   = (const float*)d_in[5];
    const float* Wo   = (const float*)d_in[6];
    const float* bo   = (const float*)d_in[7];
    float* out = (float*)d_out;

    ushort_t* Xbf  = (ushort_t*)d_ws;                  // [MM][DD]
    ushort_t* QKVb = Xbf  + (size_t)MM * DD;           // [MM][QKD]
    ushort_t* AOb  = QKVb + (size_t)MM * QKD;          // [MM][DD]
    ushort_t* Wqt  = AOb  + (size_t)MM * DD;           // [DD][DD]
    ushort_t* Wkt  = Wqt  + (size_t)DD * DD;           // [KVD][DD]
    ushort_t* Wvt  = Wkt  + (size_t)KVD * DD;          // [KVD][DD]
    ushort_t* Wot  = Wvt  + (size_t)KVD * DD;          // [DD][DD]
    ushort_t* VT   = Wot  + (size_t)DD * DD;           // [BB][KVD][SS]

    const int nprep = NCVT + 2304 + 576 + 576 + 2304;
    k_prep    <<<dim3(nprep), 256, 0, stream>>>(HS, Wq, Wk, Wv, Wo,
                                                Xbf, Wqt, Wkt, Wvt, Wot);
    k_proj    <<<dim3(480 + 192), 256, 0, stream>>>(Xbf, Wqt, Wkt, Wvt,
                                                    cosb, sinb, QKVb, VT);
    k_attn    <<<dim3(SS / 128, HEADS, BB), 256, 0, stream>>>(QKVb, VT, AOb);
    k_out_mfma<<<dim3(DD / 128, MM / 64),   256, 0, stream>>>(AOb, Wot, bo, HS, out);
}

// Round 12
// 260.121 us; speedup vs baseline: 1.1805x; 1.0348x over previous
//
#include <hip/hip_runtime.h>

#define HEADS 24
#define KVH   6
#define HD    64
#define BB    2
#define SS    2048
#define DD    1536
#define KVD   384      // KVH*HD
#define QKD   1920     // DD + KVD (Q|K only; V lives in VT)
#define MM    4096     // BB*SS

typedef unsigned short ushort_t;
typedef __attribute__((ext_vector_type(8))) short short8;
typedef __attribute__((ext_vector_type(4))) short short4v;
typedef __attribute__((ext_vector_type(4))) float f32x4;

__device__ __forceinline__ ushort_t f2bf(float f) {
    union { float f; unsigned u; } v; v.f = f;
    return (ushort_t)((v.u + 0x8000u) >> 16);
}
__device__ __forceinline__ unsigned pk2(float a, float b) {
    union { float f; unsigned u; } x, y; x.f = a; y.f = b;
    return ((x.u + 0x8000u) >> 16) | (((y.u + 0x8000u) >> 16) << 16);
}
// truncation pack (P values: common-mode cancels in softmax)
__device__ __forceinline__ unsigned pk2t(float a, float b) {
    union { float f; unsigned u; } x, y; x.f = a; y.f = b;
    return (x.u >> 16) | (y.u & 0xFFFF0000u);
}
// Schraudolph fast 2^s (±3.5% rel; cancels in p/Σp)
__device__ __forceinline__ float fexp2(float s) {
    float t = fmaf(s, 8388608.0f, 1065055420.0f);   // (127 - 0.0355) * 2^23
    union { int i; float f; } v; v.i = (int)t;
    return v.f;
}
// 16B frag read from an 8B-aligned LDS row (pitch 76): two b64 halves.
__device__ __forceinline__ short8 lds_frag8(const ushort_t* p) {
    short4v lo = *(const short4v*)p;
    short4v hi = *(const short4v*)(p + 4);
    return __builtin_shufflevector(lo, hi, 0, 1, 2, 3, 4, 5, 6, 7);
}
// async global->LDS, 16B per lane; lds ptr must be wave-uniform base.
__device__ __forceinline__ void glds16(const void* g, void* l) {
    __builtin_amdgcn_global_load_lds(
        (const __attribute__((address_space(1))) void*)g,
        (__attribute__((address_space(3))) void*)l, 16, 0, 0);
}

// ---------------------------------------------------------------------------
// K0: fused preprocessing — cvt X + 4x weight transpose-convert.
// ---------------------------------------------------------------------------
__device__ __forceinline__ void tconv_body(const float* __restrict__ in,
                                           ushort_t* __restrict__ out,
                                           int R, int C, int cb, int rb)
{
    __shared__ ushort_t tile[32][33];
    const int tx = threadIdx.x & 31, ty = threadIdx.x >> 5;
    const int c0 = cb * 32, r0 = rb * 32;
#pragma unroll
    for (int i = 0; i < 4; ++i)
        tile[ty + i * 8][tx] = f2bf(in[(size_t)(r0 + ty + i * 8) * C + c0 + tx]);
    __syncthreads();
#pragma unroll
    for (int i = 0; i < 4; ++i)
        out[(size_t)(c0 + ty + i * 8) * R + r0 + tx] = tile[tx][ty + i * 8];
}

#define NCVT (MM * DD / 4 / 256)     // 6144
__global__ __launch_bounds__(256) void k_prep(const float* __restrict__ HS,
                                              const float* __restrict__ Wq,
                                              const float* __restrict__ Wk,
                                              const float* __restrict__ Wv,
                                              const float* __restrict__ Wo,
                                              ushort_t* __restrict__ Xbf,
                                              ushort_t* __restrict__ Wqt,
                                              ushort_t* __restrict__ Wkt,
                                              ushort_t* __restrict__ Wvt,
                                              ushort_t* __restrict__ Wot)
{
    int bid = blockIdx.x;
    if (bid < NCVT) {
        int i = bid * 256 + threadIdx.x;
        float4 v = ((const float4*)HS)[i];
        uint2 o = { pk2(v.x, v.y), pk2(v.z, v.w) };
        ((uint2*)Xbf)[i] = o;
        return;
    }
    bid -= NCVT;
    if (bid < 2304) { tconv_body(Wq, Wqt, DD, DD,  bid % 48, bid / 48); return; }
    bid -= 2304;
    if (bid < 576)  { tconv_body(Wk, Wkt, DD, KVD, bid % 12, bid / 12); return; }
    bid -= 576;
    if (bid < 576)  { tconv_body(Wv, Wvt, DD, KVD, bid % 12, bid / 12); return; }
    bid -= 576;
    tconv_body(Wo, Wot, DD, DD, bid % 48, bid / 48);
}

// ---------------------------------------------------------------------------
// K1: fused projection dispatch.
//   bid <  480 : Q|K projection, 128x128 tiles + RoPE + Q-scale
//   bid >= 480 : V^T GEMM -> VT with k-PERMUTED token order within each
//                64-token block: tok j*16+t stored at 4t+j.  Attention's P
//                tile uses the same ordering, so PV is contraction-invariant
//                and P can be written with packed b64 stores.
// ---------------------------------------------------------------------------
__global__ __launch_bounds__(256) void k_proj(const ushort_t* __restrict__ Xbf,
                                              const ushort_t* __restrict__ Wqt,
                                              const ushort_t* __restrict__ Wkt,
                                              const ushort_t* __restrict__ Wvt,
                                              const float* __restrict__ cosb,
                                              const float* __restrict__ sinb,
                                              ushort_t* __restrict__ QKVb,
                                              ushort_t* __restrict__ VT)
{
    __shared__ ushort_t As[128][32];
    __shared__ ushort_t Bs[128][32];
    const int t = threadIdx.x, lane = t & 63, wave = t >> 6;
    const int n16 = lane & 15, quad = lane >> 4;
    const int wr = wave >> 1, wc = wave & 1;
    const int srow = lane >> 2;
    const int scol = (lane & 3) * 8;

    if (blockIdx.x < 480) {
        // ---------------- Q|K projection ----------------
        const int nt = blockIdx.x % 15;
        const int n0 = nt * 128;
        const int m0 = (blockIdx.x / 15) * 128;
        const ushort_t* Bt; int nl, isq;
        if (nt < 12) { Bt = Wqt; nl = n0;      isq = 1; }
        else         { Bt = Wkt; nl = n0 - DD; isq = 0; }

        const size_t aoff0 = (size_t)(m0 + wave * 16 + srow) * DD + scol;
        const size_t aoff1 = (size_t)(m0 + (wave + 4) * 16 + srow) * DD + scol;
        const size_t boff0 = (size_t)(nl + wave * 16 + srow) * DD + scol;
        const size_t boff1 = (size_t)(nl + (wave + 4) * 16 + srow) * DD + scol;
        ushort_t* lA0 = &As[wave * 16][0];
        ushort_t* lA1 = &As[(wave + 4) * 16][0];
        ushort_t* lB0 = &Bs[wave * 16][0];
        ushort_t* lB1 = &Bs[(wave + 4) * 16][0];

        f32x4 acc[4][4] = {};
        for (int k0 = 0; k0 < DD; k0 += 32) {
            __syncthreads();
            glds16(Xbf + aoff0 + k0, lA0);
            glds16(Xbf + aoff1 + k0, lA1);
            glds16(Bt  + boff0 + k0, lB0);
            glds16(Bt  + boff1 + k0, lB1);
            __syncthreads();
            short8 af[4], bf8[4];
#pragma unroll
            for (int i = 0; i < 4; ++i) af[i]  = *(const short8*)&As[wr * 64 + i * 16 + n16][quad * 8];
#pragma unroll
            for (int j = 0; j < 4; ++j) bf8[j] = *(const short8*)&Bs[wc * 64 + j * 16 + n16][quad * 8];
#pragma unroll
            for (int i = 0; i < 4; ++i)
#pragma unroll
                for (int j = 0; j < 4; ++j)
                    acc[i][j] = __builtin_amdgcn_mfma_f32_16x16x32_bf16(af[i], bf8[j], acc[i][j], 0, 0, 0);
        }

        const float QSC = 0.18033688011112042f;   // 0.125 * log2(e)
#pragma unroll
        for (int i = 0; i < 4; ++i) {
#pragma unroll
            for (int r = 0; r < 4; ++r) {
                const int row = m0 + wr * 64 + i * 16 + quad * 4 + r;
                ushort_t* outp = QKVb + (size_t)row * QKD + n0 + wc * 64 + n16;
                float v0 = acc[i][0][r], v1 = acc[i][1][r];
                float v2 = acc[i][2][r], v3 = acc[i][3][r];
                {   // partial RoPE on head dims 0..31 (Q and K)
                    const int s = row & (SS - 1);
                    float c0 = cosb[s * 32 + n16],      s0 = sinb[s * 32 + n16];
                    float c1 = cosb[s * 32 + 16 + n16], s1 = sinb[s * 32 + 16 + n16];
                    float nr = v0 * c0 - v1 * s0;
                    float ni = v1 * c1 + v0 * s1;
                    v0 = nr; v1 = ni;
                }
                if (isq) { v0 *= QSC; v1 *= QSC; v2 *= QSC; v3 *= QSC; }
                outp[0]  = f2bf(v0);
                outp[16] = f2bf(v1);
                outp[32] = f2bf(v2);
                outp[48] = f2bf(v3);
            }
        }
    } else {
        // ---------------- V^T GEMM (k-permuted epilogue) ----------------
        const int vb = blockIdx.x - 480;
        const int n0 = (vb & 31) * 128;    // tokens
        const int m0 = (vb >> 5) * 64;     // channels c

        const size_t aoff  = (size_t)(m0 + wave * 16 + srow) * DD + scol;
        const size_t boff0 = (size_t)(n0 + wave * 32 + srow) * DD + scol;
        const size_t boff1 = boff0 + (size_t)16 * DD;
        ushort_t* lA  = &As[wave * 16][0];
        ushort_t* lB0 = &Bs[wave * 32][0];
        ushort_t* lB1 = &Bs[wave * 32 + 16][0];

        f32x4 acc[2][4] = {};
        for (int k0 = 0; k0 < DD; k0 += 32) {
            __syncthreads();
            glds16(Wvt + aoff  + k0, lA);
            glds16(Xbf + boff0 + k0, lB0);
            glds16(Xbf + boff1 + k0, lB1);
            __syncthreads();
            short8 af[2], bf8[4];
#pragma unroll
            for (int i = 0; i < 2; ++i) af[i]  = *(const short8*)&As[wr * 32 + i * 16 + n16][quad * 8];
#pragma unroll
            for (int j = 0; j < 4; ++j) bf8[j] = *(const short8*)&Bs[wc * 64 + j * 16 + n16][quad * 8];
#pragma unroll
            for (int i = 0; i < 2; ++i)
#pragma unroll
                for (int j = 0; j < 4; ++j)
                    acc[i][j] = __builtin_amdgcn_mfma_f32_16x16x32_bf16(af[i], bf8[j], acc[i][j], 0, 0, 0);
        }

        const int b = n0 >> 11;            // token tile never straddles batch
        // tok = blk + j*16 + n16  stored at  blk + 4*n16 + j  (contiguous x4)
#pragma unroll
        for (int i = 0; i < 2; ++i)
#pragma unroll
            for (int r = 0; r < 4; ++r) {
                const int c = m0 + wr * 32 + i * 16 + quad * 4 + r;
                ushort_t* op = VT + ((size_t)b * KVD + c) * SS +
                               (n0 & (SS - 1)) + wc * 64 + 4 * n16;
                uint2 o = { pk2(acc[i][0][r], acc[i][1][r]),
                            pk2(acc[i][2][r], acc[i][3][r]) };
                *(uint2*)op = o;
            }
    }
}

// ---------------------------------------------------------------------------
// K3: MFMA bf16 flash attention — 128q/block, 32q/wave, fast-exp2 softmax,
// k-PERMUTED P/V layout: P row q holds p(u) at col 4*n16+jj, matching VT's
// token permutation -> P stores are packed b64 (8/lane/tile vs 32 b16).
// LDS pitch 76.  LDS 38.0 KB, grid 768 = 3/CU.
// ---------------------------------------------------------------------------
__global__ __launch_bounds__(256) void k_attn(const ushort_t* __restrict__ QKVb,
                                              const ushort_t* __restrict__ VT,
                                              ushort_t* __restrict__ AOb)
{
    __shared__ __align__(16) ushort_t Ks[64][76];
    __shared__ __align__(16) ushort_t Vs[64][76];   // Vs[d][perm(ktok)]
    __shared__ __align__(16) ushort_t Ps[128][76];

    const int t    = threadIdx.x;
    const int wave = t >> 6;
    const int quad = (t >> 4) & 3;
    const int n16  = t & 15;
    const int q0   = blockIdx.x * 128;
    const int h    = blockIdx.y;
    const int b    = blockIdx.z;
    const int kh   = h >> 2;

    const int sr = t >> 2;            // 0..63 staging row
    const int sc = (t & 3) * 8;       // K staging col
    const int vc = (t & 3) * 16;      // V staging col

    // loop-invariant Q A-frags from global (pre-scaled by 0.125*log2e)
    short8 qf[2][2];
#pragma unroll
    for (int m = 0; m < 2; ++m)
#pragma unroll
        for (int kc = 0; kc < 2; ++kc)
            qf[m][kc] = *(const short8*)(QKVb +
                (size_t)(b * SS + q0 + wave * 32 + m * 16 + n16) * QKD +
                h * HD + kc * 32 + quad * 8);

    float l_p[2][4] = {};             // per-lane partial row sums
    f32x4 acc_o[2][4] = {};

    const ushort_t* Kbase = QKVb + (size_t)(b * SS) * QKD + DD + kh * HD;
    const ushort_t* Vbase = VT + ((size_t)b * KVD + kh * 64) * SS;

    for (int kt = 0; kt < SS / 64; ++kt) {
        const int k0 = kt * 64;
        __syncthreads();   // prev-tile readers of Ks/Vs done
        {
            const ushort_t* Kg = Kbase + (size_t)(k0 + sr) * QKD + sc;
            uint4 kv0 = *(const uint4*)(Kg);
            uint4 kv1 = *(const uint4*)(Kg + 32);
            *(uint2*)&Ks[sr][sc]      = make_uint2(kv0.x, kv0.y);
            *(uint2*)&Ks[sr][sc + 4]  = make_uint2(kv0.z, kv0.w);
            *(uint2*)&Ks[sr][sc + 32] = make_uint2(kv1.x, kv1.y);
            *(uint2*)&Ks[sr][sc + 36] = make_uint2(kv1.z, kv1.w);
            const ushort_t* Vg = Vbase + (size_t)sr * SS + k0 + vc;
            uint4 vv0 = *(const uint4*)(Vg);
            uint4 vv1 = *(const uint4*)(Vg + 8);
            *(uint2*)&Vs[sr][vc]      = make_uint2(vv0.x, vv0.y);
            *(uint2*)&Vs[sr][vc + 4]  = make_uint2(vv0.z, vv0.w);
            *(uint2*)&Vs[sr][vc + 8]  = make_uint2(vv1.x, vv1.y);
            *(uint2*)&Vs[sr][vc + 12] = make_uint2(vv1.z, vv1.w);
        }
        __syncthreads();

        // ---- QK^T: S[32q][64k] per wave ----
        f32x4 s_acc[2][4] = {};
#pragma unroll
        for (int kc = 0; kc < 2; ++kc) {
            short8 bf[4];
#pragma unroll
            for (int jj = 0; jj < 4; ++jj)
                bf[jj] = lds_frag8(&Ks[jj * 16 + n16][kc * 32 + quad * 8]);
#pragma unroll
            for (int m = 0; m < 2; ++m)
#pragma unroll
                for (int jj = 0; jj < 4; ++jj)
                    s_acc[m][jj] = __builtin_amdgcn_mfma_f32_16x16x32_bf16(
                        qf[m][kc], bf[jj], s_acc[m][jj], 0, 0, 0);
        }

        // ---- p = 2^s; partial l; packed b64 P stores (permuted cols) ----
#pragma unroll
        for (int m = 0; m < 2; ++m)
#pragma unroll
            for (int r = 0; r < 4; ++r) {
                float p0 = fexp2(s_acc[m][0][r]);
                float p1 = fexp2(s_acc[m][1][r]);
                float p2 = fexp2(s_acc[m][2][r]);
                float p3 = fexp2(s_acc[m][3][r]);
                uint2 o = { pk2t(p0, p1), pk2t(p2, p3) };
                *(uint2*)&Ps[wave * 32 + m * 16 + quad * 4 + r][4 * n16] = o;
                l_p[m][r] += (p0 + p1) + (p2 + p3);
            }

        // ---- PV (Ps rows wave-private; same-wave RAW via lgkmcnt) ----
#pragma unroll
        for (int kc = 0; kc < 2; ++kc) {
            short8 vb[4];
#pragma unroll
            for (int dd = 0; dd < 4; ++dd)
                vb[dd] = lds_frag8(&Vs[dd * 16 + n16][kc * 32 + quad * 8]);
#pragma unroll
            for (int m = 0; m < 2; ++m) {
                short8 pa = lds_frag8(&Ps[wave * 32 + m * 16 + n16][kc * 32 + quad * 8]);
#pragma unroll
                for (int dd = 0; dd < 4; ++dd)
                    acc_o[m][dd] = __builtin_amdgcn_mfma_f32_16x16x32_bf16(
                        pa, vb[dd], acc_o[m][dd], 0, 0, 0);
            }
        }
    }

    // ---- epilogue: one lane-reduction of l, then O/l ----
#pragma unroll
    for (int m = 0; m < 2; ++m) {
        float inv[4];
#pragma unroll
        for (int r = 0; r < 4; ++r) {
            float s = l_p[m][r];
#pragma unroll
            for (int msk = 1; msk < 16; msk <<= 1)
                s += __shfl_xor(s, msk);
            inv[r] = 1.0f / s;
        }
#pragma unroll
        for (int dd = 0; dd < 4; ++dd)
#pragma unroll
            for (int r = 0; r < 4; ++r) {
                int q = q0 + wave * 32 + m * 16 + quad * 4 + r;
                AOb[(size_t)(b * SS + q) * DD + h * HD + dd * 16 + n16] =
                    f2bf(acc_o[m][dd][r] * inv[r]);
            }
    }
}

// ---------------------------------------------------------------------------
// K4: MFMA out-proj.  out[MM][DD](fp32) = AOb @ Wot^T + bo + HS.
// 64m x 128n tiles, grid (DD/128=12) x (MM/64=64) = 768 = exactly 3/CU.
// ---------------------------------------------------------------------------
__global__ __launch_bounds__(256) void k_out_mfma(const ushort_t* __restrict__ AOb,
                                                  const ushort_t* __restrict__ Wot,
                                                  const float* __restrict__ bo,
                                                  const float* __restrict__ HS,
                                                  float* __restrict__ out)
{
    __shared__ ushort_t As[64][32];    // AOb rows (m)
    __shared__ ushort_t Bs[128][32];   // Wot rows (n)
    const int t = threadIdx.x, lane = t & 63, wave = t >> 6;
    const int n16 = lane & 15, quad = lane >> 4;
    const int wr = wave >> 1, wc = wave & 1;
    const int n0 = blockIdx.x * 128;
    const int m0 = blockIdx.y * 64;

    const int srow = lane >> 2;
    const int scol = (lane & 3) * 8;
    const size_t aoff  = (size_t)(m0 + wave * 16 + srow) * DD + scol;
    const size_t boff0 = (size_t)(n0 + wave * 32 + srow) * DD + scol;
    const size_t boff1 = boff0 + (size_t)16 * DD;
    ushort_t* lA  = &As[wave * 16][0];
    ushort_t* lB0 = &Bs[wave * 32][0];
    ushort_t* lB1 = &Bs[wave * 32 + 16][0];

    f32x4 acc[2][4] = {};
    for (int k0 = 0; k0 < DD; k0 += 32) {
        __syncthreads();
        glds16(AOb + aoff  + k0, lA);
        glds16(Wot + boff0 + k0, lB0);
        glds16(Wot + boff1 + k0, lB1);
        __syncthreads();
        short8 af[2], bf8[4];
#pragma unroll
        for (int i = 0; i < 2; ++i) af[i]  = *(const short8*)&As[wr * 32 + i * 16 + n16][quad * 8];
#pragma unroll
        for (int j = 0; j < 4; ++j) bf8[j] = *(const short8*)&Bs[wc * 64 + j * 16 + n16][quad * 8];
#pragma unroll
        for (int i = 0; i < 2; ++i)
#pragma unroll
            for (int j = 0; j < 4; ++j)
                acc[i][j] = __builtin_amdgcn_mfma_f32_16x16x32_bf16(af[i], bf8[j], acc[i][j], 0, 0, 0);
    }

    const int colb = n0 + wc * 64 + n16;
    float bo4[4];
#pragma unroll
    for (int j = 0; j < 4; ++j) bo4[j] = bo[colb + j * 16];
#pragma unroll
    for (int i = 0; i < 2; ++i) {
#pragma unroll
        for (int r = 0; r < 4; ++r) {
            const int row = m0 + wr * 32 + i * 16 + quad * 4 + r;
            float* op = out + (size_t)row * DD + colb;
            const float* hp = HS + (size_t)row * DD + colb;
#pragma unroll
            for (int j = 0; j < 4; ++j)
                op[j * 16] = acc[i][j][r] + bo4[j] + hp[j * 16];
        }
    }
}

extern "C" void kernel_launch(void* const* d_in, const int* in_sizes, int n_in,
                              void* d_out, int out_size, void* d_ws, size_t ws_size,
                              hipStream_t stream)
{
    const float* HS   = (const float*)d_in[0];
    const float* cosb = (const float*)d_in[1];
    const float* sinb = (const float*)d_in[2];
    const float* Wq   = (const float*)d_in[3];
    const float* Wk   = (const float*)d_in[4];
    const float* Wv   = (const float*)d_in[5];
    const float* Wo   = (const float*)d_in[6];
    const float* bo   = (const float*)d_in[7];
    float* out = (float*)d_out;

    ushort_t* Xbf  = (ushort_t*)d_ws;                  // [MM][DD]
    ushort_t* QKVb = Xbf  + (size_t)MM * DD;           // [MM][QKD]
    ushort_t* AOb  = QKVb + (size_t)MM * QKD;          // [MM][DD]
    ushort_t* Wqt  = AOb  + (size_t)MM * DD;           // [DD][DD]
    ushort_t* Wkt  = Wqt  + (size_t)DD * DD;           // [KVD][DD]
    ushort_t* Wvt  = Wkt  + (size_t)KVD * DD;          // [KVD][DD]
    ushort_t* Wot  = Wvt  + (size_t)KVD * DD;          // [DD][DD]
    ushort_t* VT   = Wot  + (size_t)DD * DD;           // [BB][KVD][SS] (k-permuted)

    const int nprep = NCVT + 2304 + 576 + 576 + 2304;
    k_prep    <<<dim3(nprep), 256, 0, stream>>>(HS, Wq, Wk, Wv, Wo,
                                                Xbf, Wqt, Wkt, Wvt, Wot);
    k_proj    <<<dim3(480 + 192), 256, 0, stream>>>(Xbf, Wqt, Wkt, Wvt,
                                                    cosb, sinb, QKVb, VT);
    k_attn    <<<dim3(SS / 128, HEADS, BB), 256, 0, stream>>>(QKVb, VT, AOb);
    k_out_mfma<<<dim3(DD / 128, MM / 64),   256, 0, stream>>>(AOb, Wot, bo, HS, out);
}